// Round 4
// baseline (1665.423 us; speedup 1.0000x reference)
//
#include <hip/hip_runtime.h>
#include <stdint.h>

// ---------------- problem constants ----------------
constexpr int Bn = 4, Sn = 4096, En = 1024, Hn = 16, Dn = 64;
constexpr int FFNdim = 4096, SEGn = 512, NSEGn = 8;
constexpr int NTOK = Bn * Sn;              // 16384 token rows
constexpr float SCALEf = 0.125f;           // 1/sqrt(D)

typedef __attribute__((ext_vector_type(8))) short bf16x8;  // MFMA A/B frag (8 bf16)
typedef __attribute__((ext_vector_type(4))) short s16x4;
typedef __attribute__((ext_vector_type(4))) float f32x4;   // MFMA C/D frag

__device__ __forceinline__ short f2bf(float f) {           // RNE fp32->bf16
  union { float f; unsigned u; } x; x.f = f;
  unsigned r = (x.u + 0x7FFFu + ((x.u >> 16) & 1u)) >> 16;
  return (short)(unsigned short)r;
}
__device__ __forceinline__ float bf2f(short s) {
  union { unsigned u; float f; } x; x.u = ((unsigned)(unsigned short)s) << 16; return x.f;
}
__device__ __forceinline__ float sigmaf(float x) {         // elu(x)+1
  return x > 0.f ? x + 1.f : expf(x);
}

// ---------------- fp32 -> bf16 convert ----------------
__global__ __launch_bounds__(256) void cvt_bf16(const float* __restrict__ in,
                                                short* __restrict__ out, int n) {
  int i = (blockIdx.x * 256 + threadIdx.x) * 8;
  if (i >= n) return;
  float4 a = *(const float4*)(in + i);
  float4 b = *(const float4*)(in + i + 4);
  bf16x8 o;
  o[0]=f2bf(a.x); o[1]=f2bf(a.y); o[2]=f2bf(a.z); o[3]=f2bf(a.w);
  o[4]=f2bf(b.x); o[5]=f2bf(b.y); o[6]=f2bf(b.z); o[7]=f2bf(b.w);
  *(bf16x8*)(out + i) = o;
}

// ------------- transpose fp32 [K][N] -> bf16 [N][K] -------------
__global__ __launch_bounds__(256) void transpose_bf16(const float* __restrict__ w,
                                                      short* __restrict__ wt,
                                                      int K, int N) {
  __shared__ float tile[32][33];
  int bx = blockIdx.x * 32;                 // n tile
  int by = blockIdx.y * 32;                 // k tile
  int tx = threadIdx.x & 31, ty = threadIdx.x >> 5;   // 32 x 8
  #pragma unroll
  for (int i = 0; i < 4; ++i)
    tile[ty + i*8][tx] = w[(size_t)(by + ty + i*8) * N + bx + tx];
  __syncthreads();
  #pragma unroll
  for (int i = 0; i < 4; ++i)
    wt[(size_t)(bx + ty + i*8) * K + by + tx] = f2bf(tile[tx][ty + i*8]);
}

// ------------- bf16 MFMA GEMM: C[M,N] = A[M,K] @ BT[N,K]^T -------------
// Conservative structure: reg-staged LDS (no global_load_lds), padded
// [128][40] rows (80B stride -> 16B aligned, bank-conflict-free fragment reads).
// 128x128 tile, BK=32, 256 threads (4 waves, 2x2 wave grid, 64x64 per wave).
template<bool BIAS, bool RELU, bool OUTBF>
__global__ __launch_bounds__(256) void gemm_bt(
    const short* __restrict__ A, const short* __restrict__ BT,
    const float* __restrict__ bias, float* __restrict__ Cf,
    short* __restrict__ Cb, int M, int N, int K)
{
  __shared__ short As[128][40];   // 32 data + 8 pad
  __shared__ short Bs[128][40];
  const int t = threadIdx.x;
  const int m0 = blockIdx.y * 128;
  const int n0 = blockIdx.x * 128;
  const int wave = t >> 6, lane = t & 63;
  const int wr = (wave >> 1) * 64, wc = (wave & 1) * 64;
  const int fr = lane & 15, kg = (lane >> 4) * 8;

  f32x4 acc[4][4] = {};

  // staging map: 512 chunks of 8 bf16 per tile; thread covers chunk t and t+256
  const int ar0 = t >> 2,        ac0 = (t & 3) * 8;
  const int ar1 = 64 + (t >> 2), ac1 = ac0;

  for (int kt = 0; kt < K; kt += 32) {
    bf16x8 a0 = *(const bf16x8*)(A  + (size_t)(m0 + ar0) * K + kt + ac0);
    bf16x8 a1 = *(const bf16x8*)(A  + (size_t)(m0 + ar1) * K + kt + ac1);
    bf16x8 b0 = *(const bf16x8*)(BT + (size_t)(n0 + ar0) * K + kt + ac0);
    bf16x8 b1 = *(const bf16x8*)(BT + (size_t)(n0 + ar1) * K + kt + ac1);
    __syncthreads();   // previous iteration's fragment reads complete
    *(bf16x8*)(&As[ar0][ac0]) = a0;
    *(bf16x8*)(&As[ar1][ac1]) = a1;
    *(bf16x8*)(&Bs[ar0][ac0]) = b0;
    *(bf16x8*)(&Bs[ar1][ac1]) = b1;
    __syncthreads();
    bf16x8 af[4], bfr[4];
    #pragma unroll
    for (int i = 0; i < 4; ++i) af[i]  = *(const bf16x8*)(&As[wr + i*16 + fr][kg]);
    #pragma unroll
    for (int j = 0; j < 4; ++j) bfr[j] = *(const bf16x8*)(&Bs[wc + j*16 + fr][kg]);
    #pragma unroll
    for (int i = 0; i < 4; ++i)
      #pragma unroll
      for (int j = 0; j < 4; ++j)
        acc[i][j] = __builtin_amdgcn_mfma_f32_16x16x32_bf16(af[i], bfr[j], acc[i][j], 0, 0, 0);
  }

  // epilogue: C/D layout col = lane&15, row = (lane>>4)*4 + reg  [m89-verified]
  const int orow = (lane >> 4) * 4;
  #pragma unroll
  for (int j = 0; j < 4; ++j) {
    const int col = n0 + wc + j*16 + fr;
    const float bv = BIAS ? bias[col] : 0.f;
    #pragma unroll
    for (int i = 0; i < 4; ++i) {
      #pragma unroll
      for (int rr = 0; rr < 4; ++rr) {
        const int row = m0 + wr + i*16 + orow + rr;
        float vv = acc[i][j][rr] + bv;
        if (RELU) vv = fmaxf(vv, 0.f);
        if (OUTBF) Cb[(size_t)row * N + col] = f2bf(vv);
        else       Cf[(size_t)row * N + col] = vv;
      }
    }
  }
}

// ------------- per-segment memory increments: dM = sigma(k)^T v, dz = sum sigma(k) -------------
// grid: NSEG*B*H blocks (s*64 + b*16 + h), 256 threads; k,v are bf16
__global__ __launch_bounds__(256) void seg_kv(const short* __restrict__ k,
                                              const short* __restrict__ v,
                                              float* __restrict__ dM,
                                              float* __restrict__ dz)
{
  const int s = blockIdx.x >> 6;
  const int bh = blockIdx.x & 63;
  const int b = bh >> 4, h = bh & 15;
  const int t = threadIdx.x;
  const int tx = t & 15, ty = t >> 4;
  __shared__ float sk[32][68];
  __shared__ float sv[32][68];
  float acc[4][4] = {};
  float zac = 0.f;
  const size_t base = (size_t)(b * Sn + s * SEGn) * En + h * Dn;

  for (int tt = 0; tt < SEGn; tt += 32) {
    __syncthreads();
    {
      int rr = t >> 3, cc = (t & 7) * 8;
      const short* kp = k + base + (size_t)(tt + rr) * En + cc;
      const short* vp = v + base + (size_t)(tt + rr) * En + cc;
      bf16x8 k8 = *(const bf16x8*)kp;
      bf16x8 v8 = *(const bf16x8*)vp;
      #pragma unroll
      for (int j = 0; j < 8; ++j) {
        sk[rr][cc + j] = sigmaf(bf2f(k8[j]));
        sv[rr][cc + j] = bf2f(v8[j]);
      }
    }
    __syncthreads();
    #pragma unroll 4
    for (int u = 0; u < 32; ++u) {
      float ad[4], ae[4];
      #pragma unroll
      for (int i = 0; i < 4; ++i) ad[i] = sk[u][ty + 16*i];
      #pragma unroll
      for (int j = 0; j < 4; ++j) ae[j] = sv[u][tx + 16*j];
      #pragma unroll
      for (int i = 0; i < 4; ++i)
        #pragma unroll
        for (int j = 0; j < 4; ++j)
          acc[i][j] += ad[i] * ae[j];
    }
    if (t < 64) {
      #pragma unroll 8
      for (int u = 0; u < 32; ++u) zac += sk[u][t];
    }
  }
  const size_t obase = (size_t)blockIdx.x * 4096;
  #pragma unroll
  for (int i = 0; i < 4; ++i)
    #pragma unroll
    for (int j = 0; j < 4; ++j)
      dM[obase + (size_t)(ty + 16*i) * 64 + tx + 16*j] = acc[i][j];
  if (t < 64) dz[(size_t)blockIdx.x * 64 + t] = zac;
}

// ------------- exclusive prefix scans over segments (IN-PLACE) -------------
__global__ __launch_bounds__(256) void scan_m(float* __restrict__ buf,
                                              float* __restrict__ ctx) {
  const int idx = blockIdx.x * 256 + threadIdx.x;   // < 262144 = B*H*D*D
  float run = 0.f;
  #pragma unroll
  for (int s = 0; s < NSEGn; ++s) {
    const size_t o = (size_t)s * 262144 + idx;
    float d = buf[o];
    buf[o] = run;          // exclusive prefix, in place
    run += d;
  }
  ctx[idx] = run;          // final M -> output tuple element 2
}
__global__ __launch_bounds__(256) void scan_z(float* __restrict__ buf) {
  const int idx = blockIdx.x * 256 + threadIdx.x;   // < 4096 = B*H*D
  float run = 0.f;
  #pragma unroll
  for (int s = 0; s < NSEGn; ++s) {
    const size_t o = (size_t)s * 4096 + idx;
    float d = buf[o];
    buf[o] = run;
    run += d;
  }
}

// ------------- local attention + memory retrieval + gate -------------
// Register-blocked fp32: thread = (rg = t>>4: 4 q-rows, cg = t&15: 4 keys / 4 dims).
// Each LDS float4 feeds 16 FMAs. K/V/M tile swizzled: phys slot = slot ^ ((row>>2)&7).
// grid: (8 row-blocks, NSEG*B*H); 256 threads.
__global__ __launch_bounds__(256) void attn_local(
    const short* __restrict__ q, const short* __restrict__ k,
    const short* __restrict__ v, const float* __restrict__ Mex,
    const float* __restrict__ zex, const float* __restrict__ beta,
    short* __restrict__ out)
{
  const int rblk = blockIdx.x;
  const int sbh = blockIdx.y;                 // s*64 + b*16 + h
  const int s = sbh >> 6, bh = sbh & 63, b = bh >> 4, h = bh & 15;
  const int t = threadIdx.x;
  const int rg = t >> 4, cg = t & 15;

  __shared__ float qs[64][68];
  __shared__ float kvb[64 * 64];   // time-shared k / v / M, swizzled float4 slots
  __shared__ float ps[64][68];     // P row-major: ps[row][key]
  __shared__ float zs[64];

  #define KV4(row, slot) (((float4*)kvb) + ((row) * 16 + ((slot) ^ (((row) >> 2) & 7))))

  const size_t segbase = (size_t)(b * Sn + s * SEGn) * En + h * Dn;
  const size_t qrow0 = (size_t)(b * Sn + s * SEGn + rblk * 64);

  // ---- stage q tile (bf16 -> fp32 LDS) ----
  const int rr = t >> 2, sc = t & 3;          // staging map: row rr, 16 cols at sc*16
  {
    const short* qp = q + (qrow0 + rr) * En + h * Dn + sc * 16;
    bf16x8 q0 = *(const bf16x8*)qp;
    bf16x8 q1 = *(const bf16x8*)(qp + 8);
    #pragma unroll
    for (int j = 0; j < 8; ++j) {
      qs[rr][sc*16 + j]     = bf2f(q0[j]);
      qs[rr][sc*16 + 8 + j] = bf2f(q1[j]);
    }
  }

  float m_run[4], l_run[4], acc[4][4];
  #pragma unroll
  for (int j = 0; j < 4; ++j) {
    m_run[j] = -1e30f; l_run[j] = 0.f;
    #pragma unroll
    for (int c = 0; c < 4; ++c) acc[j][c] = 0.f;
  }

  for (int kt = 0; kt < 8; ++kt) {
    const short* kp = k + segbase + (size_t)(kt*64 + rr) * En + sc * 16;
    const short* vp = v + segbase + (size_t)(kt*64 + rr) * En + sc * 16;
    bf16x8 kr0 = *(const bf16x8*)kp, kr1 = *(const bf16x8*)(kp + 8);
    bf16x8 vr0 = *(const bf16x8*)vp, vr1 = *(const bf16x8*)(vp + 8);

    __syncthreads();   // previous tile's PV reads done
    {
      float4 w0 = {bf2f(kr0[0]), bf2f(kr0[1]), bf2f(kr0[2]), bf2f(kr0[3])};
      float4 w1 = {bf2f(kr0[4]), bf2f(kr0[5]), bf2f(kr0[6]), bf2f(kr0[7])};
      float4 w2 = {bf2f(kr1[0]), bf2f(kr1[1]), bf2f(kr1[2]), bf2f(kr1[3])};
      float4 w3 = {bf2f(kr1[4]), bf2f(kr1[5]), bf2f(kr1[6]), bf2f(kr1[7])};
      *KV4(rr, sc*4+0) = w0; *KV4(rr, sc*4+1) = w1;
      *KV4(rr, sc*4+2) = w2; *KV4(rr, sc*4+3) = w3;
    }
    __syncthreads();   // k tile visible

    // ---- scores: 4 rows x 4 keys per thread ----
    float scv[4][4] = {};
    for (int d0 = 0; d0 < 64; d0 += 4) {
      float4 qv[4], kx[4];
      #pragma unroll
      for (int j = 0; j < 4; ++j) qv[j] = *(const float4*)&qs[rg*4 + j][d0];
      #pragma unroll
      for (int c = 0; c < 4; ++c) kx[c] = *KV4(cg*4 + c, d0 >> 2);
      #pragma unroll
      for (int j = 0; j < 4; ++j)
        #pragma unroll
        for (int c = 0; c < 4; ++c)
          scv[j][c] += qv[j].x*kx[c].x + qv[j].y*kx[c].y + qv[j].z*kx[c].z + qv[j].w*kx[c].w;
    }

    // ---- online softmax (row reduce over 16 lanes: cg group) ----
    float pj[4][4];
    #pragma unroll
    for (int j = 0; j < 4; ++j) {
      float ml = -1e30f;
      #pragma unroll
      for (int c = 0; c < 4; ++c) { scv[j][c] *= SCALEf; ml = fmaxf(ml, scv[j][c]); }
      ml = fmaxf(ml, __shfl_xor(ml, 1));
      ml = fmaxf(ml, __shfl_xor(ml, 2));
      ml = fmaxf(ml, __shfl_xor(ml, 4));
      ml = fmaxf(ml, __shfl_xor(ml, 8));
      const float mn = fmaxf(m_run[j], ml);
      const float corr = expf(m_run[j] - mn);
      m_run[j] = mn;
      float rs = 0.f;
      #pragma unroll
      for (int c = 0; c < 4; ++c) { pj[j][c] = expf(scv[j][c] - mn); rs += pj[j][c]; }
      rs += __shfl_xor(rs, 1);
      rs += __shfl_xor(rs, 2);
      rs += __shfl_xor(rs, 4);
      rs += __shfl_xor(rs, 8);
      l_run[j] = l_run[j] * corr + rs;
      #pragma unroll
      for (int c = 0; c < 4; ++c) acc[j][c] *= corr;
    }
    __syncthreads();   // all k reads done before v overwrite

    #pragma unroll
    for (int j = 0; j < 4; ++j) {
      float4 pw = {pj[j][0], pj[j][1], pj[j][2], pj[j][3]};
      *(float4*)&ps[rg*4 + j][cg*4] = pw;
    }
    {
      float4 w0 = {bf2f(vr0[0]), bf2f(vr0[1]), bf2f(vr0[2]), bf2f(vr0[3])};
      float4 w1 = {bf2f(vr0[4]), bf2f(vr0[5]), bf2f(vr0[6]), bf2f(vr0[7])};
      float4 w2 = {bf2f(vr1[0]), bf2f(vr1[1]), bf2f(vr1[2]), bf2f(vr1[3])};
      float4 w3 = {bf2f(vr1[4]), bf2f(vr1[5]), bf2f(vr1[6]), bf2f(vr1[7])};
      *KV4(rr, sc*4+0) = w0; *KV4(rr, sc*4+1) = w1;
      *KV4(rr, sc*4+2) = w2; *KV4(rr, sc*4+3) = w3;
    }
    __syncthreads();   // ps + v tile visible

    // ---- PV: 4 rows x 4 dims (dims cg*4..cg*4+3 = float4 slot cg) ----
    for (int kk = 0; kk < 64; ++kk) {
      float4 vv = *KV4(kk, cg);
      float p0 = ps[rg*4+0][kk], p1 = ps[rg*4+1][kk];
      float p2 = ps[rg*4+2][kk], p3 = ps[rg*4+3][kk];
      acc[0][0] += p0*vv.x; acc[0][1] += p0*vv.y; acc[0][2] += p0*vv.z; acc[0][3] += p0*vv.w;
      acc[1][0] += p1*vv.x; acc[1][1] += p1*vv.y; acc[1][2] += p1*vv.z; acc[1][3] += p1*vv.w;
      acc[2][0] += p2*vv.x; acc[2][1] += p2*vv.y; acc[2][2] += p2*vv.z; acc[2][3] += p2*vv.w;
      acc[3][0] += p3*vv.x; acc[3][1] += p3*vv.y; acc[3][2] += p3*vv.z; acc[3][3] += p3*vv.w;
    }
  }

  __syncthreads();   // last PV reads done
  // ---- stage M_excl + z ----
  {
    const float* mp = Mex + (size_t)sbh * 4096 + (size_t)rr * 64 + sc * 16;
    float4 m0v = *(const float4*)(mp + 0);
    float4 m1v = *(const float4*)(mp + 4);
    float4 m2v = *(const float4*)(mp + 8);
    float4 m3v = *(const float4*)(mp + 12);
    *KV4(rr, sc*4+0) = m0v; *KV4(rr, sc*4+1) = m1v;
    *KV4(rr, sc*4+2) = m2v; *KV4(rr, sc*4+3) = m3v;
    if (t < 64) zs[t] = zex[(size_t)sbh * 64 + t];
  }
  __syncthreads();

  // ---- memory retrieval: am = sigma(q) @ M, den = sigma(q).z + eps ----
  float am[4][4] = {};
  float den[4] = {1e-6f, 1e-6f, 1e-6f, 1e-6f};
  for (int d = 0; d < 64; ++d) {
    float4 mv = *KV4(d, cg);
    const float zd = zs[d];
    #pragma unroll
    for (int j = 0; j < 4; ++j) {
      const float sq = sigmaf(qs[rg*4 + j][d]);
      den[j] += sq * zd;
      am[j][0] += sq * mv.x; am[j][1] += sq * mv.y;
      am[j][2] += sq * mv.z; am[j][3] += sq * mv.w;
    }
  }

  const float g = 1.f / (1.f + expf(-beta[h]));
  #pragma unroll
  for (int j = 0; j < 4; ++j) {
    const float rd = 1.f / den[j];
    const float rl = 1.f / l_run[j];
    s16x4 ov;
    #pragma unroll
    for (int c = 0; c < 4; ++c)
      ov[c] = f2bf(g * am[j][c] * rd + (1.f - g) * acc[j][c] * rl);
    *(s16x4*)(out + (qrow0 + rg*4 + j) * En + h * Dn + cg * 4) = ov;
  }
  #undef KV4
}

// ------------- LN1: h = LN(a + res), a fp32, res fp32 -> bf16 out -------------
__global__ __launch_bounds__(256) void ln1_kernel(
    const float* __restrict__ a, const float* __restrict__ res,
    const float* __restrict__ gw, const float* __restrict__ bw,
    short* __restrict__ outb)
{
  const int row = blockIdx.x;
  const size_t base = (size_t)row * En;
  const int t = threadIdx.x;
  float4 av = *(const float4*)(a + base + t*4);
  float4 rv = *(const float4*)(res + base + t*4);
  const float v0 = av.x + rv.x, v1 = av.y + rv.y, v2 = av.z + rv.z, v3 = av.w + rv.w;
  float s = v0 + v1 + v2 + v3;
  float sq = v0*v0 + v1*v1 + v2*v2 + v3*v3;
  #pragma unroll
  for (int off = 32; off >= 1; off >>= 1) {
    s  += __shfl_xor(s, off);
    sq += __shfl_xor(sq, off);
  }
  __shared__ float reds[4], redq[4];
  const int wave = t >> 6, lane = t & 63;
  if (lane == 0) { reds[wave] = s; redq[wave] = sq; }
  __syncthreads();
  const float st = reds[0] + reds[1] + reds[2] + reds[3];
  const float qt = redq[0] + redq[1] + redq[2] + redq[3];
  const float mean = st * (1.f / En);
  const float var = qt * (1.f / En) - mean * mean;
  const float rstd = rsqrtf(var + 1e-5f);
  float4 gv = *(const float4*)(gw + t*4);
  float4 bv = *(const float4*)(bw + t*4);
  s16x4 ob;
  ob[0] = f2bf((v0 - mean) * rstd * gv.x + bv.x);
  ob[1] = f2bf((v1 - mean) * rstd * gv.y + bv.y);
  ob[2] = f2bf((v2 - mean) * rstd * gv.z + bv.z);
  ob[3] = f2bf((v3 - mean) * rstd * gv.w + bv.w);
  *(s16x4*)(outb + base + t*4) = ob;
}

// ------------- LN2: y = LN(a + res), a fp32 (in-place ok), res bf16 -> fp32 out -------------
__global__ __launch_bounds__(256) void ln2_kernel(
    const float* __restrict__ a, const short* __restrict__ res,
    const float* __restrict__ gw, const float* __restrict__ bw,
    float* __restrict__ outf)
{
  const int row = blockIdx.x;
  const size_t base = (size_t)row * En;
  const int t = threadIdx.x;
  float4 av = *(const float4*)(a + base + t*4);
  s16x4 rb = *(const s16x4*)(res + base + t*4);
  const float v0 = av.x + bf2f(rb[0]), v1 = av.y + bf2f(rb[1]);
  const float v2 = av.z + bf2f(rb[2]), v3 = av.w + bf2f(rb[3]);
  float s = v0 + v1 + v2 + v3;
  float sq = v0*v0 + v1*v1 + v2*v2 + v3*v3;
  #pragma unroll
  for (int off = 32; off >= 1; off >>= 1) {
    s  += __shfl_xor(s, off);
    sq += __shfl_xor(sq, off);
  }
  __shared__ float reds[4], redq[4];
  const int wave = t >> 6, lane = t & 63;
  if (lane == 0) { reds[wave] = s; redq[wave] = sq; }
  __syncthreads();
  const float st = reds[0] + reds[1] + reds[2] + reds[3];
  const float qt = redq[0] + redq[1] + redq[2] + redq[3];
  const float mean = st * (1.f / En);
  const float var = qt * (1.f / En) - mean * mean;
  const float rstd = rsqrtf(var + 1e-5f);
  float4 gv = *(const float4*)(gw + t*4);
  float4 bv = *(const float4*)(bw + t*4);
  float4 of;
  of.x = (v0 - mean) * rstd * gv.x + bv.x;
  of.y = (v1 - mean) * rstd * gv.y + bv.y;
  of.z = (v2 - mean) * rstd * gv.z + bv.z;
  of.w = (v3 - mean) * rstd * gv.w + bv.w;
  *(float4*)(outf + base + t*4) = of;
}

// ---------------- host launcher ----------------
// Workspace budget (defensive, ~112 MiB of d_ws peak + d_out used as fp32 scratch):
//   xb 32MiB | weights 24MiB | qb/kb/vb/attnb 4x32MiB contiguous (mid aliases)
//   dM 8MiB (in-place scan) | dz 128KiB (in-place scan)
//   h (bf16) aliases xb | attnproj & FFN2-out use d_out's y region
extern "C" void kernel_launch(void* const* d_in, const int* in_sizes, int n_in,
                              void* d_out, int out_size, void* d_ws, size_t ws_size,
                              hipStream_t stream) {
  const float* x     = (const float*)d_in[0];
  const float* wq    = (const float*)d_in[1];
  const float* wk    = (const float*)d_in[2];
  const float* wv    = (const float*)d_in[3];
  const float* wo    = (const float*)d_in[4];
  const float* beta  = (const float*)d_in[5];
  const float* ln1g  = (const float*)d_in[6];
  const float* ln1b  = (const float*)d_in[7];
  const float* w1    = (const float*)d_in[8];
  const float* b1    = (const float*)d_in[9];
  const float* w2    = (const float*)d_in[10];
  const float* b2    = (const float*)d_in[11];
  const float* ln2g  = (const float*)d_in[12];
  const float* ln2b  = (const float*)d_in[13];

  float* y_out   = (float*)d_out;                          // [NTOK, E] fp32
  float* ctx_out = y_out + (size_t)NTOK * En;              // [B,H,D,D] fp32

  char* ws = (char*)d_ws;
  size_t off = 0;
  auto alloc = [&](size_t bytes) { char* p = ws + off; off += (bytes + 255) & ~(size_t)255; return p; };
  short* xb    = (short*)alloc((size_t)NTOK * En * 2);         // 32 MiB
  short* wqT   = (short*)alloc((size_t)En * En * 2);           // 2 MiB
  short* wkT   = (short*)alloc((size_t)En * En * 2);
  short* wvT   = (short*)alloc((size_t)En * En * 2);
  short* woT   = (short*)alloc((size_t)En * En * 2);
  short* w1T   = (short*)alloc((size_t)FFNdim * En * 2);       // 8 MiB [FFN][E]
  short* w2T   = (short*)alloc((size_t)En * FFNdim * 2);       // 8 MiB [E][FFN]
  short* qb    = (short*)alloc((size_t)NTOK * En * 2);         // 32 MiB (contig block start)
  short* kb    = (short*)alloc((size_t)NTOK * En * 2);         // 32 MiB
  short* vb    = (short*)alloc((size_t)NTOK * En * 2);         // 32 MiB
  short* attnb = (short*)alloc((size_t)NTOK * En * 2);         // 32 MiB (contig block end)
  float* dM    = (float*)alloc((size_t)NSEGn * 262144 * 4);    // 8 MiB
  float* dz    = (float*)alloc((size_t)NSEGn * 4096 * 4);      // 128 KiB

  // lifetime aliases
  short* mid   = qb;                 // [NTOK, FFN] bf16 = 128 MiB over dead q/k/v/attnb
  short* hb    = xb;                 // h in bf16 over dead xb
  float* attnproj = y_out;           // out-proj fp32 scratch in d_out's y region
  float* fbuf     = y_out;           // FFN2 fp32 out, LN2 runs in-place per row

  // 1. convert x to bf16
  cvt_bf16<<<(NTOK * En) / 2048, 256, 0, stream>>>(x, xb, NTOK * En);

  // 2. transpose-convert all weights
  transpose_bf16<<<dim3(En/32, En/32), 256, 0, stream>>>(wq, wqT, En, En);
  transpose_bf16<<<dim3(En/32, En/32), 256, 0, stream>>>(wk, wkT, En, En);
  transpose_bf16<<<dim3(En/32, En/32), 256, 0, stream>>>(wv, wvT, En, En);
  transpose_bf16<<<dim3(En/32, En/32), 256, 0, stream>>>(wo, woT, En, En);
  transpose_bf16<<<dim3(FFNdim/32, En/32), 256, 0, stream>>>(w1, w1T, En, FFNdim);
  transpose_bf16<<<dim3(En/32, FFNdim/32), 256, 0, stream>>>(w2, w2T, FFNdim, En);

  // 3. QKV projections (bf16 MFMA, bf16 out)
  dim3 gQKV(En/128, NTOK/128);
  gemm_bt<false,false,true><<<gQKV, 256, 0, stream>>>(xb, wqT, nullptr, nullptr, qb, NTOK, En, En);
  gemm_bt<false,false,true><<<gQKV, 256, 0, stream>>>(xb, wkT, nullptr, nullptr, kb, NTOK, En, En);
  gemm_bt<false,false,true><<<gQKV, 256, 0, stream>>>(xb, wvT, nullptr, nullptr, vb, NTOK, En, En);

  // 4. per-segment memory increments + in-place exclusive prefix scans
  seg_kv<<<NSEGn * Bn * Hn, 256, 0, stream>>>(kb, vb, dM, dz);
  scan_m<<<262144 / 256, 256, 0, stream>>>(dM, ctx_out);
  scan_z<<<4096 / 256, 256, 0, stream>>>(dz);

  // 5. local attention + retrieval + gate -> bf16 attn
  attn_local<<<dim3(8, NSEGn * Bn * Hn), 256, 0, stream>>>(qb, kb, vb, dM, dz, beta, attnb);

  // 6. output projection -> fp32 scratch in d_out
  gemm_bt<false,false,false><<<gQKV, 256, 0, stream>>>(attnb, woT, nullptr, attnproj, nullptr, NTOK, En, En);

  // 7. h = LN(x + attn_out) -> bf16 (over dead xb)
  ln1_kernel<<<NTOK, 256, 0, stream>>>(attnproj, x, ln1g, ln1b, hb);

  // 8. FFN1: relu(h @ w1 + b1) -> bf16 mid (over dead q/k/v/attnb)
  gemm_bt<true,true,true><<<dim3(FFNdim/128, NTOK/128), 256, 0, stream>>>(hb, w1T, b1, nullptr, mid, NTOK, FFNdim, En);

  // 9. FFN2: mid @ w2 + b2 -> fp32 in d_out's y region
  gemm_bt<true,false,false><<<dim3(En/128, NTOK/128), 256, 0, stream>>>(mid, w2T, b2, fbuf, nullptr, NTOK, En, FFNdim);

  // 10. y = LN(f + h), in-place on d_out
  ln2_kernel<<<NTOK, 256, 0, stream>>>(fbuf, hb, ln2g, ln2b, y_out);
}

// Round 5
// 1162.053 us; speedup vs baseline: 1.4332x; 1.4332x over previous
//
#include <hip/hip_runtime.h>
#include <stdint.h>

// ---------------- problem constants ----------------
constexpr int Bn = 4, Sn = 4096, En = 1024, Hn = 16, Dn = 64;
constexpr int FFNdim = 4096, SEGn = 512, NSEGn = 8;
constexpr int NTOK = Bn * Sn;              // 16384 token rows
constexpr float SCALEf = 0.125f;           // 1/sqrt(D)

typedef __attribute__((ext_vector_type(8))) short bf16x8;  // MFMA A/B frag (8 bf16)
typedef __attribute__((ext_vector_type(4))) short s16x4;
typedef __attribute__((ext_vector_type(4))) float f32x4;   // MFMA C/D frag
typedef __attribute__((ext_vector_type(4))) unsigned int u32x4;

__device__ __forceinline__ short f2bf(float f) {           // RNE fp32->bf16
  union { float f; unsigned u; } x; x.f = f;
  unsigned r = (x.u + 0x7FFFu + ((x.u >> 16) & 1u)) >> 16;
  return (short)(unsigned short)r;
}
__device__ __forceinline__ float bf2f(short s) {
  union { unsigned u; float f; } x; x.u = ((unsigned)(unsigned short)s) << 16; return x.f;
}
__device__ __forceinline__ float sigmaf(float x) {         // elu(x)+1
  return x > 0.f ? x + 1.f : expf(x);
}
__device__ __forceinline__ unsigned pack2bf(float a, float b) {
  return (unsigned)(unsigned short)f2bf(a) | ((unsigned)(unsigned short)f2bf(b) << 16);
}

// ---------------- fp32 -> bf16 convert ----------------
__global__ __launch_bounds__(256) void cvt_bf16(const float* __restrict__ in,
                                                short* __restrict__ out, int n) {
  int i = (blockIdx.x * 256 + threadIdx.x) * 8;
  if (i >= n) return;
  float4 a = *(const float4*)(in + i);
  float4 b = *(const float4*)(in + i + 4);
  bf16x8 o;
  o[0]=f2bf(a.x); o[1]=f2bf(a.y); o[2]=f2bf(a.z); o[3]=f2bf(a.w);
  o[4]=f2bf(b.x); o[5]=f2bf(b.y); o[6]=f2bf(b.z); o[7]=f2bf(b.w);
  *(bf16x8*)(out + i) = o;
}

// ------------- transpose fp32 [K][N] -> bf16 [N][K] -------------
__global__ __launch_bounds__(256) void transpose_bf16(const float* __restrict__ w,
                                                      short* __restrict__ wt,
                                                      int K, int N) {
  __shared__ float tile[32][33];
  int bx = blockIdx.x * 32;                 // n tile
  int by = blockIdx.y * 32;                 // k tile
  int tx = threadIdx.x & 31, ty = threadIdx.x >> 5;   // 32 x 8
  #pragma unroll
  for (int i = 0; i < 4; ++i)
    tile[ty + i*8][tx] = w[(size_t)(by + ty + i*8) * N + bx + tx];
  __syncthreads();
  #pragma unroll
  for (int i = 0; i < 4; ++i)
    wt[(size_t)(bx + ty + i*8) * K + by + tx] = f2bf(tile[tx][ty + i*8]);
}

// ------------- bf16 MFMA GEMM: C[M,N] = A[M,K] @ BT[N,K]^T -------------
// reg-staged LDS, padded [128][40] rows. 128x128 tile, BK=32, 256 threads.
template<bool BIAS, bool RELU, bool OUTBF>
__global__ __launch_bounds__(256) void gemm_bt(
    const short* __restrict__ A, const short* __restrict__ BT,
    const float* __restrict__ bias, float* __restrict__ Cf,
    short* __restrict__ Cb, int M, int N, int K)
{
  __shared__ short As[128][40];   // 32 data + 8 pad
  __shared__ short Bs[128][40];
  const int t = threadIdx.x;
  const int m0 = blockIdx.y * 128;
  const int n0 = blockIdx.x * 128;
  const int wave = t >> 6, lane = t & 63;
  const int wr = (wave >> 1) * 64, wc = (wave & 1) * 64;
  const int fr = lane & 15, kg = (lane >> 4) * 8;

  f32x4 acc[4][4] = {};

  const int ar0 = t >> 2,        ac0 = (t & 3) * 8;
  const int ar1 = 64 + (t >> 2), ac1 = ac0;

  for (int kt = 0; kt < K; kt += 32) {
    bf16x8 a0 = *(const bf16x8*)(A  + (size_t)(m0 + ar0) * K + kt + ac0);
    bf16x8 a1 = *(const bf16x8*)(A  + (size_t)(m0 + ar1) * K + kt + ac1);
    bf16x8 b0 = *(const bf16x8*)(BT + (size_t)(n0 + ar0) * K + kt + ac0);
    bf16x8 b1 = *(const bf16x8*)(BT + (size_t)(n0 + ar1) * K + kt + ac1);
    __syncthreads();   // previous iteration's fragment reads complete
    *(bf16x8*)(&As[ar0][ac0]) = a0;
    *(bf16x8*)(&As[ar1][ac1]) = a1;
    *(bf16x8*)(&Bs[ar0][ac0]) = b0;
    *(bf16x8*)(&Bs[ar1][ac1]) = b1;
    __syncthreads();
    bf16x8 af[4], bfr[4];
    #pragma unroll
    for (int i = 0; i < 4; ++i) af[i]  = *(const bf16x8*)(&As[wr + i*16 + fr][kg]);
    #pragma unroll
    for (int j = 0; j < 4; ++j) bfr[j] = *(const bf16x8*)(&Bs[wc + j*16 + fr][kg]);
    #pragma unroll
    for (int i = 0; i < 4; ++i)
      #pragma unroll
      for (int j = 0; j < 4; ++j)
        acc[i][j] = __builtin_amdgcn_mfma_f32_16x16x32_bf16(af[i], bfr[j], acc[i][j], 0, 0, 0);
  }

  const int orow = (lane >> 4) * 4;
  #pragma unroll
  for (int j = 0; j < 4; ++j) {
    const int col = n0 + wc + j*16 + fr;
    const float bv = BIAS ? bias[col] : 0.f;
    #pragma unroll
    for (int i = 0; i < 4; ++i) {
      #pragma unroll
      for (int rr = 0; rr < 4; ++rr) {
        const int row = m0 + wr + i*16 + orow + rr;
        float vv = acc[i][j][rr] + bv;
        if (RELU) vv = fmaxf(vv, 0.f);
        if (OUTBF) Cb[(size_t)row * N + col] = f2bf(vv);
        else       Cf[(size_t)row * N + col] = vv;
      }
    }
  }
}

// ------------- per-segment memory increments: dM = sigma(k)^T v, dz = sum sigma(k) -------------
__global__ __launch_bounds__(256) void seg_kv(const short* __restrict__ k,
                                              const short* __restrict__ v,
                                              float* __restrict__ dM,
                                              float* __restrict__ dz)
{
  const int s = blockIdx.x >> 6;
  const int bh = blockIdx.x & 63;
  const int b = bh >> 4, h = bh & 15;
  const int t = threadIdx.x;
  const int tx = t & 15, ty = t >> 4;
  __shared__ float sk[32][68];
  __shared__ float sv[32][68];
  float acc[4][4] = {};
  float zac = 0.f;
  const size_t base = (size_t)(b * Sn + s * SEGn) * En + h * Dn;

  for (int tt = 0; tt < SEGn; tt += 32) {
    __syncthreads();
    {
      int rr = t >> 3, cc = (t & 7) * 8;
      const short* kp = k + base + (size_t)(tt + rr) * En + cc;
      const short* vp = v + base + (size_t)(tt + rr) * En + cc;
      bf16x8 k8 = *(const bf16x8*)kp;
      bf16x8 v8 = *(const bf16x8*)vp;
      #pragma unroll
      for (int j = 0; j < 8; ++j) {
        sk[rr][cc + j] = sigmaf(bf2f(k8[j]));
        sv[rr][cc + j] = bf2f(v8[j]);
      }
    }
    __syncthreads();
    #pragma unroll 4
    for (int u = 0; u < 32; ++u) {
      float ad[4], ae[4];
      #pragma unroll
      for (int i = 0; i < 4; ++i) ad[i] = sk[u][ty + 16*i];
      #pragma unroll
      for (int j = 0; j < 4; ++j) ae[j] = sv[u][tx + 16*j];
      #pragma unroll
      for (int i = 0; i < 4; ++i)
        #pragma unroll
        for (int j = 0; j < 4; ++j)
          acc[i][j] += ad[i] * ae[j];
    }
    if (t < 64) {
      #pragma unroll 8
      for (int u = 0; u < 32; ++u) zac += sk[u][t];
    }
  }
  const size_t obase = (size_t)blockIdx.x * 4096;
  #pragma unroll
  for (int i = 0; i < 4; ++i)
    #pragma unroll
    for (int j = 0; j < 4; ++j)
      dM[obase + (size_t)(ty + 16*i) * 64 + tx + 16*j] = acc[i][j];
  if (t < 64) dz[(size_t)blockIdx.x * 64 + t] = zac;
}

// ------------- exclusive prefix scans over segments (IN-PLACE) -------------
__global__ __launch_bounds__(256) void scan_m(float* __restrict__ buf,
                                              float* __restrict__ ctx) {
  const int idx = blockIdx.x * 256 + threadIdx.x;   // < 262144
  float run = 0.f;
  #pragma unroll
  for (int s = 0; s < NSEGn; ++s) {
    const size_t o = (size_t)s * 262144 + idx;
    float d = buf[o];
    buf[o] = run;
    run += d;
  }
  ctx[idx] = run;
}
__global__ __launch_bounds__(256) void scan_z(float* __restrict__ buf) {
  const int idx = blockIdx.x * 256 + threadIdx.x;   // < 4096
  float run = 0.f;
  #pragma unroll
  for (int s = 0; s < NSEGn; ++s) {
    const size_t o = (size_t)s * 4096 + idx;
    float d = buf[o];
    buf[o] = run;
    run += d;
  }
}

// ------------- MFMA local attention + memory retrieval + gate -------------
// 2 waves/block, 128 q-rows/block, grid (4, NSEG*B*H).
// Swapped QK^T: accs = mfma(K,Q) -> C[key][qrow]; softmax in-lane + shfl_xor(16,32).
// P redistributed to PV A-frags via lane shuffles (no P in LDS).
// V (and later M^T) staged transposed as packed bf16-pairs in VtM[64][36] u32.
__global__ __launch_bounds__(128, 2) void attn_mfma(
    const short* __restrict__ q, const short* __restrict__ k,
    const short* __restrict__ v, const float* __restrict__ Mex,
    const float* __restrict__ zex, const float* __restrict__ beta,
    short* __restrict__ out)
{
  const int rblk = blockIdx.x;               // 0..3 (128-row chunk of the segment)
  const int sbh  = blockIdx.y;               // s*64 + b*16 + h
  const int s = sbh >> 6, bh = sbh & 63, b = bh >> 4, h = bh & 15;
  const int t = threadIdx.x;
  const int w = t >> 6, lane = t & 63;
  const int fr = lane & 15, hi = lane >> 4;

  __shared__ short Qs[128][72];              // stride 72: 16B-aligned rows, no 16-way conflict
  __shared__ short Ks[64][72];
  __shared__ unsigned VtM[64][36];           // V^T pair-packed (row=d, col=key-pair); later M^T
  __shared__ float zs[64];

  const size_t segbase = (size_t)(b * Sn + s * SEGn) * En + h * Dn;
  const int row0 = rblk * 128;
  const size_t qg = segbase + (size_t)row0 * En;

  // ---- stage Q (128 rows x 64 bf16) ----
  #pragma unroll
  for (int r2 = 0; r2 < 2; ++r2) {
    const int qr = (t >> 1) + r2 * 64, qh = (t & 1) * 32;
    const short* qp = q + qg + (size_t)qr * En + qh;
    #pragma unroll
    for (int c = 0; c < 4; ++c)
      *(bf16x8*)&Qs[qr][qh + c*8] = *(const bf16x8*)(qp + c*8);
  }
  if (t < 64) zs[t] = zex[(size_t)sbh * 64 + t];

  float m_run[4], l_run[4];
  #pragma unroll
  for (int j = 0; j < 4; ++j) { m_run[j] = -1e30f; l_run[j] = 0.f; }
  f32x4 acco[4][4] = {};

  for (int kt = 0; kt < 8; ++kt) {
    __syncthreads();                         // prior tile's LDS reads done
    // ---- stage K tile ----
    {
      const int kr = t >> 1, kh = (t & 1) * 32;
      const short* kp = k + segbase + (size_t)(kt*64 + kr) * En + kh;
      #pragma unroll
      for (int c = 0; c < 4; ++c)
        *(bf16x8*)&Ks[kr][kh + c*8] = *(const bf16x8*)(kp + c*8);
    }
    // ---- stage V transposed, pair-packed ----
    {
      const int p = t & 31, g2 = t >> 5;     // rows 2p,2p+1; cols g2*16..+15
      const short* vp = v + segbase + (size_t)(kt*64 + 2*p) * En + g2*16;
      bf16x8 r0a = *(const bf16x8*)(vp);
      bf16x8 r0b = *(const bf16x8*)(vp + 8);
      bf16x8 r1a = *(const bf16x8*)(vp + En);
      bf16x8 r1b = *(const bf16x8*)(vp + En + 8);
      #pragma unroll
      for (int i = 0; i < 8; ++i) {
        VtM[g2*16 + i][p]     = (unsigned)(unsigned short)r0a[i] | ((unsigned)(unsigned short)r1a[i] << 16);
        VtM[g2*16 + 8 + i][p] = (unsigned)(unsigned short)r0b[i] | ((unsigned)(unsigned short)r1b[i] << 16);
      }
    }
    __syncthreads();

    // ---- QK^T swapped: accs[i][j] = C[key = i*16+hi*4+rr][qrow = j*16+fr] ----
    f32x4 accs[4][4] = {};
    #pragma unroll
    for (int s2 = 0; s2 < 2; ++s2) {
      bf16x8 ak[4], bq[4];
      #pragma unroll
      for (int i = 0; i < 4; ++i) ak[i] = *(const bf16x8*)&Ks[i*16 + fr][s2*32 + hi*8];
      #pragma unroll
      for (int j = 0; j < 4; ++j) bq[j] = *(const bf16x8*)&Qs[w*64 + j*16 + fr][s2*32 + hi*8];
      #pragma unroll
      for (int i = 0; i < 4; ++i)
        #pragma unroll
        for (int j = 0; j < 4; ++j)
          accs[i][j] = __builtin_amdgcn_mfma_f32_16x16x32_bf16(ak[i], bq[j], accs[i][j], 0, 0, 0);
    }

    // ---- online softmax (per qrow j*16+fr) + pack P to bf16 pairs ----
    unsigned pk0[4][4], pk1[4][4];           // [j][i]: rr(0,1) and rr(2,3)
    float corr[4];
    #pragma unroll
    for (int j = 0; j < 4; ++j) {
      float p16[4][4];
      float ml = -1e30f;
      #pragma unroll
      for (int i = 0; i < 4; ++i)
        #pragma unroll
        for (int rr = 0; rr < 4; ++rr) {
          p16[i][rr] = accs[i][j][rr] * SCALEf;
          ml = fmaxf(ml, p16[i][rr]);
        }
      ml = fmaxf(ml, __shfl_xor(ml, 16));
      ml = fmaxf(ml, __shfl_xor(ml, 32));
      const float mn = fmaxf(m_run[j], ml);
      corr[j] = expf(m_run[j] - mn);
      m_run[j] = mn;
      float rs = 0.f;
      #pragma unroll
      for (int i = 0; i < 4; ++i)
        #pragma unroll
        for (int rr = 0; rr < 4; ++rr) { p16[i][rr] = expf(p16[i][rr] - mn); rs += p16[i][rr]; }
      rs += __shfl_xor(rs, 16);
      rs += __shfl_xor(rs, 32);
      l_run[j] = l_run[j] * corr[j] + rs;
      #pragma unroll
      for (int i = 0; i < 4; ++i) {
        pk0[j][i] = pack2bf(p16[i][0], p16[i][1]);
        pk1[j][i] = pack2bf(p16[i][2], p16[i][3]);
      }
    }

    // ---- rescale acco by corr (out row = mi*16+hi*4+rr; holder lane = hi*4+rr) ----
    #pragma unroll
    for (int mi = 0; mi < 4; ++mi) {
      float c4[4];
      #pragma unroll
      for (int rr = 0; rr < 4; ++rr) c4[rr] = __shfl(corr[mi], hi*4 + rr);
      #pragma unroll
      for (int n2 = 0; n2 < 4; ++n2)
        #pragma unroll
        for (int rr = 0; rr < 4; ++rr) acco[mi][n2][rr] *= c4[rr];
    }

    // ---- PV: A-frag via shuffle redistribution; B-frag from VtM ----
    // target key = s2*32 + hi*8 + jj: src lane = fr + 16*((hi&1)*2 + (jj>>2)),
    // src reg i = 2*s2 + (hi>>1), rr = jj&3.
    const int sl = fr + 32 * (hi & 1);
    const int sh = sl + 16;
    const int selhi = hi >> 1;
    #pragma unroll
    for (int s2 = 0; s2 < 2; ++s2) {
      bf16x8 bv[4];
      #pragma unroll
      for (int n2 = 0; n2 < 4; ++n2)
        bv[n2] = *(const bf16x8*)&VtM[n2*16 + fr][s2*16 + hi*4];
      #pragma unroll
      for (int j = 0; j < 4; ++j) {
        unsigned wa0 = (unsigned)__shfl((int)pk0[j][2*s2],     sl);
        unsigned wa1 = (unsigned)__shfl((int)pk1[j][2*s2],     sl);
        unsigned wa2 = (unsigned)__shfl((int)pk0[j][2*s2],     sh);
        unsigned wa3 = (unsigned)__shfl((int)pk1[j][2*s2],     sh);
        unsigned wb0 = (unsigned)__shfl((int)pk0[j][2*s2 + 1], sl);
        unsigned wb1 = (unsigned)__shfl((int)pk1[j][2*s2 + 1], sl);
        unsigned wb2 = (unsigned)__shfl((int)pk0[j][2*s2 + 1], sh);
        unsigned wb3 = (unsigned)__shfl((int)pk1[j][2*s2 + 1], sh);
        u32x4 uw;
        uw[0] = selhi ? wb0 : wa0;
        uw[1] = selhi ? wb1 : wa1;
        uw[2] = selhi ? wb2 : wa2;
        uw[3] = selhi ? wb3 : wa3;
        bf16x8 pa = __builtin_bit_cast(bf16x8, uw);
        #pragma unroll
        for (int n2 = 0; n2 < 4; ++n2)
          acco[j][n2] = __builtin_amdgcn_mfma_f32_16x16x32_bf16(pa, bv[n2], acco[j][n2], 0, 0, 0);
      }
    }
  }

  // ---- retrieval phase ----
  __syncthreads();                           // PV reads of VtM done
  // stage M^T pair-packed: VtM[e][d-pair] = (M[2dp][e], M[2dp+1][e])
  {
    const int dp = t >> 2, eg = t & 3;
    const float* m0p = Mex + (size_t)sbh * 4096 + (size_t)(2*dp) * 64 + eg*16;
    const float* m1p = m0p + 64;
    #pragma unroll
    for (int c = 0; c < 4; ++c) {
      float4 a = *(const float4*)(m0p + c*4);
      float4 bq4 = *(const float4*)(m1p + c*4);
      VtM[eg*16 + c*4 + 0][dp] = pack2bf(a.x, bq4.x);
      VtM[eg*16 + c*4 + 1][dp] = pack2bf(a.y, bq4.y);
      VtM[eg*16 + c*4 + 2][dp] = pack2bf(a.z, bq4.z);
      VtM[eg*16 + c*4 + 3][dp] = pack2bf(a.w, bq4.w);
    }
  }
  // den per thread (block-local q-row t): sigma(q[t]) . z + EPS
  float den_acc = 1e-6f;
  #pragma unroll
  for (int c = 0; c < 8; ++c) {
    bf16x8 q8 = *(const bf16x8*)&Qs[t][c*8];
    #pragma unroll
    for (int e = 0; e < 8; ++e)
      den_acc += sigmaf(bf2f(q8[e])) * zs[c*8 + e];
  }
  const float rdv = 1.f / den_acc;
  __syncthreads();                           // M^T visible

  // accr = sigma(Q) @ M  (C[qrow][e])
  f32x4 accr[4][4] = {};
  #pragma unroll
  for (int s2 = 0; s2 < 2; ++s2) {
    bf16x8 aq[4], bm[4];
    #pragma unroll
    for (int mi = 0; mi < 4; ++mi) {
      bf16x8 q8 = *(const bf16x8*)&Qs[w*64 + mi*16 + fr][s2*32 + hi*8];
      bf16x8 sq8;
      #pragma unroll
      for (int e = 0; e < 8; ++e) sq8[e] = f2bf(sigmaf(bf2f(q8[e])));
      aq[mi] = sq8;
    }
    #pragma unroll
    for (int n2 = 0; n2 < 4; ++n2)
      bm[n2] = *(const bf16x8*)&VtM[n2*16 + fr][s2*16 + hi*4];
    #pragma unroll
    for (int mi = 0; mi < 4; ++mi)
      #pragma unroll
      for (int n2 = 0; n2 < 4; ++n2)
        accr[mi][n2] = __builtin_amdgcn_mfma_f32_16x16x32_bf16(aq[mi], bm[n2], accr[mi][n2], 0, 0, 0);
  }

  // ---- combine + write ----
  const float g = 1.f / (1.f + expf(-beta[h]));
  float rli[4];
  #pragma unroll
  for (int j = 0; j < 4; ++j) rli[j] = 1.f / l_run[j];
  #pragma unroll
  for (int mi = 0; mi < 4; ++mi) {
    float rl4[4], rd4[4];
    #pragma unroll
    for (int rr = 0; rr < 4; ++rr) {
      rl4[rr] = __shfl(rli[mi], hi*4 + rr);              // l holder: lane fr = hi*4+rr, j = mi
      rd4[rr] = __shfl(rdv, mi*16 + hi*4 + rr);          // den holder: lane = local row
    }
    #pragma unroll
    for (int n2 = 0; n2 < 4; ++n2) {
      #pragma unroll
      for (int rr = 0; rr < 4; ++rr) {
        const int lrow = w*64 + mi*16 + hi*4 + rr;
        float val = g * accr[mi][n2][rr] * rd4[rr] + (1.f - g) * acco[mi][n2][rr] * rl4[rr];
        out[qg + (size_t)lrow * En + n2*16 + fr] = f2bf(val);
      }
    }
  }
}

// ------------- LN1: h = LN(a + res), a fp32, res fp32 -> bf16 out -------------
__global__ __launch_bounds__(256) void ln1_kernel(
    const float* __restrict__ a, const float* __restrict__ res,
    const float* __restrict__ gw, const float* __restrict__ bw,
    short* __restrict__ outb)
{
  const int row = blockIdx.x;
  const size_t base = (size_t)row * En;
  const int t = threadIdx.x;
  float4 av = *(const float4*)(a + base + t*4);
  float4 rv = *(const float4*)(res + base + t*4);
  const float v0 = av.x + rv.x, v1 = av.y + rv.y, v2 = av.z + rv.z, v3 = av.w + rv.w;
  float s = v0 + v1 + v2 + v3;
  float sq = v0*v0 + v1*v1 + v2*v2 + v3*v3;
  #pragma unroll
  for (int off = 32; off >= 1; off >>= 1) {
    s  += __shfl_xor(s, off);
    sq += __shfl_xor(sq, off);
  }
  __shared__ float reds[4], redq[4];
  const int wave = t >> 6, lane = t & 63;
  if (lane == 0) { reds[wave] = s; redq[wave] = sq; }
  __syncthreads();
  const float st = reds[0] + reds[1] + reds[2] + reds[3];
  const float qt = redq[0] + redq[1] + redq[2] + redq[3];
  const float mean = st * (1.f / En);
  const float var = qt * (1.f / En) - mean * mean;
  const float rstd = rsqrtf(var + 1e-5f);
  float4 gv = *(const float4*)(gw + t*4);
  float4 bv = *(const float4*)(bw + t*4);
  s16x4 ob;
  ob[0] = f2bf((v0 - mean) * rstd * gv.x + bv.x);
  ob[1] = f2bf((v1 - mean) * rstd * gv.y + bv.y);
  ob[2] = f2bf((v2 - mean) * rstd * gv.z + bv.z);
  ob[3] = f2bf((v3 - mean) * rstd * gv.w + bv.w);
  *(s16x4*)(outb + base + t*4) = ob;
}

// ------------- LN2: y = LN(a + res), a fp32 (in-place ok), res bf16 -> fp32 out -------------
__global__ __launch_bounds__(256) void ln2_kernel(
    const float* __restrict__ a, const short* __restrict__ res,
    const float* __restrict__ gw, const float* __restrict__ bw,
    float* __restrict__ outf)
{
  const int row = blockIdx.x;
  const size_t base = (size_t)row * En;
  const int t = threadIdx.x;
  float4 av = *(const float4*)(a + base + t*4);
  s16x4 rb = *(const s16x4*)(res + base + t*4);
  const float v0 = av.x + bf2f(rb[0]), v1 = av.y + bf2f(rb[1]);
  const float v2 = av.z + bf2f(rb[2]), v3 = av.w + bf2f(rb[3]);
  float s = v0 + v1 + v2 + v3;
  float sq = v0*v0 + v1*v1 + v2*v2 + v3*v3;
  #pragma unroll
  for (int off = 32; off >= 1; off >>= 1) {
    s  += __shfl_xor(s, off);
    sq += __shfl_xor(sq, off);
  }
  __shared__ float reds[4], redq[4];
  const int wave = t >> 6, lane = t & 63;
  if (lane == 0) { reds[wave] = s; redq[wave] = sq; }
  __syncthreads();
  const float st = reds[0] + reds[1] + reds[2] + reds[3];
  const float qt = redq[0] + redq[1] + redq[2] + redq[3];
  const float mean = st * (1.f / En);
  const float var = qt * (1.f / En) - mean * mean;
  const float rstd = rsqrtf(var + 1e-5f);
  float4 gv = *(const float4*)(gw + t*4);
  float4 bv = *(const float4*)(bw + t*4);
  float4 of;
  of.x = (v0 - mean) * rstd * gv.x + bv.x;
  of.y = (v1 - mean) * rstd * gv.y + bv.y;
  of.z = (v2 - mean) * rstd * gv.z + bv.z;
  of.w = (v3 - mean) * rstd * gv.w + bv.w;
  *(float4*)(outf + base + t*4) = of;
}

// ---------------- host launcher ----------------
extern "C" void kernel_launch(void* const* d_in, const int* in_sizes, int n_in,
                              void* d_out, int out_size, void* d_ws, size_t ws_size,
                              hipStream_t stream) {
  const float* x     = (const float*)d_in[0];
  const float* wq    = (const float*)d_in[1];
  const float* wk    = (const float*)d_in[2];
  const float* wv    = (const float*)d_in[3];
  const float* wo    = (const float*)d_in[4];
  const float* beta  = (const float*)d_in[5];
  const float* ln1g  = (const float*)d_in[6];
  const float* ln1b  = (const float*)d_in[7];
  const float* w1    = (const float*)d_in[8];
  const float* b1    = (const float*)d_in[9];
  const float* w2    = (const float*)d_in[10];
  const float* b2    = (const float*)d_in[11];
  const float* ln2g  = (const float*)d_in[12];
  const float* ln2b  = (const float*)d_in[13];

  float* y_out   = (float*)d_out;                          // [NTOK, E] fp32
  float* ctx_out = y_out + (size_t)NTOK * En;              // [B,H,D,D] fp32

  char* ws = (char*)d_ws;
  size_t off = 0;
  auto alloc = [&](size_t bytes) { char* p = ws + off; off += (bytes + 255) & ~(size_t)255; return p; };
  short* xb    = (short*)alloc((size_t)NTOK * En * 2);         // 32 MiB
  short* wqT   = (short*)alloc((size_t)En * En * 2);           // 2 MiB
  short* wkT   = (short*)alloc((size_t)En * En * 2);
  short* wvT   = (short*)alloc((size_t)En * En * 2);
  short* woT   = (short*)alloc((size_t)En * En * 2);
  short* w1T   = (short*)alloc((size_t)FFNdim * En * 2);       // 8 MiB [FFN][E]
  short* w2T   = (short*)alloc((size_t)En * FFNdim * 2);       // 8 MiB [E][FFN]
  short* qb    = (short*)alloc((size_t)NTOK * En * 2);         // 32 MiB (contig block start)
  short* kb    = (short*)alloc((size_t)NTOK * En * 2);         // 32 MiB
  short* vb    = (short*)alloc((size_t)NTOK * En * 2);         // 32 MiB
  short* attnb = (short*)alloc((size_t)NTOK * En * 2);         // 32 MiB (contig block end)
  float* dM    = (float*)alloc((size_t)NSEGn * 262144 * 4);    // 8 MiB
  float* dz    = (float*)alloc((size_t)NSEGn * 4096 * 4);      // 128 KiB

  // lifetime aliases
  short* mid   = qb;                 // [NTOK, FFN] bf16 over dead q/k/v/attnb
  short* hb    = xb;                 // h in bf16 over dead xb
  float* attnproj = y_out;           // out-proj fp32 scratch in d_out's y region
  float* fbuf     = y_out;           // FFN2 fp32 out, LN2 runs in-place per row

  // 1. convert x to bf16
  cvt_bf16<<<(NTOK * En) / 2048, 256, 0, stream>>>(x, xb, NTOK * En);

  // 2. transpose-convert all weights
  transpose_bf16<<<dim3(En/32, En/32), 256, 0, stream>>>(wq, wqT, En, En);
  transpose_bf16<<<dim3(En/32, En/32), 256, 0, stream>>>(wk, wkT, En, En);
  transpose_bf16<<<dim3(En/32, En/32), 256, 0, stream>>>(wv, wvT, En, En);
  transpose_bf16<<<dim3(En/32, En/32), 256, 0, stream>>>(wo, woT, En, En);
  transpose_bf16<<<dim3(FFNdim/32, En/32), 256, 0, stream>>>(w1, w1T, En, FFNdim);
  transpose_bf16<<<dim3(En/32, FFNdim/32), 256, 0, stream>>>(w2, w2T, FFNdim, En);

  // 3. QKV projections (bf16 MFMA, bf16 out)
  dim3 gQKV(En/128, NTOK/128);
  gemm_bt<false,false,true><<<gQKV, 256, 0, stream>>>(xb, wqT, nullptr, nullptr, qb, NTOK, En, En);
  gemm_bt<false,false,true><<<gQKV, 256, 0, stream>>>(xb, wkT, nullptr, nullptr, kb, NTOK, En, En);
  gemm_bt<false,false,true><<<gQKV, 256, 0, stream>>>(xb, wvT, nullptr, nullptr, vb, NTOK, En, En);

  // 4. per-segment memory increments + in-place exclusive prefix scans
  seg_kv<<<NSEGn * Bn * Hn, 256, 0, stream>>>(kb, vb, dM, dz);
  scan_m<<<262144 / 256, 256, 0, stream>>>(dM, ctx_out);
  scan_z<<<4096 / 256, 256, 0, stream>>>(dz);

  // 5. MFMA local attention + retrieval + gate -> bf16 attn
  attn_mfma<<<dim3(4, NSEGn * Bn * Hn), 128, 0, stream>>>(qb, kb, vb, dM, dz, beta, attnb);

  // 6. output projection -> fp32 scratch in d_out
  gemm_bt<false,false,false><<<gQKV, 256, 0, stream>>>(attnb, woT, nullptr, attnproj, nullptr, NTOK, En, En);

  // 7. h = LN(x + attn_out) -> bf16 (over dead xb)
  ln1_kernel<<<NTOK, 256, 0, stream>>>(attnproj, x, ln1g, ln1b, hb);

  // 8. FFN1: relu(h @ w1 + b1) -> bf16 mid (over dead q/k/v/attnb)
  gemm_bt<true,true,true><<<dim3(FFNdim/128, NTOK/128), 256, 0, stream>>>(hb, w1T, b1, nullptr, mid, NTOK, FFNdim, En);

  // 9. FFN2: mid @ w2 + b2 -> fp32 in d_out's y region
  gemm_bt<true,false,false><<<dim3(En/128, NTOK/128), 256, 0, stream>>>(mid, w2T, b2, fbuf, nullptr, NTOK, En, FFNdim);

  // 10. y = LN(f + h), in-place on d_out
  ln2_kernel<<<NTOK, 256, 0, stream>>>(fbuf, hb, ln2g, ln2b, y_out);
}